// Round 2
// baseline (164.371 us; speedup 1.0000x reference)
//
#include <hip/hip_runtime.h>
#include <stdint.h>

#define TDIM 512
#define NDIM 256
#define BDIM 128
#define CGAP 5
#define DELTA_C 0.05f
#define CH 16                    // timesteps per register chunk
#define NCH (TDIM / CH)          // 32 chunks

extern "C" __global__ void __launch_bounds__(64)
stca_kernel(const float* __restrict__ vmem, const int* __restrict__ labels,
            const float* __restrict__ ratio_p, float* __restrict__ out) {
  const int lane = threadIdx.x;            // neuron within 64-wide slice
  const int blk  = blockIdx.x;             // 512 blocks: (b, n-quarter)
  const int b    = blk >> 2;
  const int n0   = (blk & 3) << 6;
  const int n    = n0 + lane;

  const float ratio = ratio_p[0];
  const int   label = labels[b * NDIM + n];
  // lane-private trace base: v[t] = g[t * NDIM]; consecutive lanes adjacent in
  // memory at fixed t -> every global_load_dword is a coalesced 256 B txn.
  const float* g = vmem + (size_t)b * TDIM * NDIM + n;

  // streaming scan state
  int   last_spike = -1000;
  int   nclu = 0, cur_count = 0, best_count = 0x7fffffff;
  float cur_max = -INFINITY;      // max v over [cur_first .. t]
  float cur_maxlast = -INFINITY;  // max v over [cur_first .. last spike]
  float best_max = -INFINITY;     // span-max of best (min-count, first-tie) cluster
  float umax = -INFINITY;         // max v over unmasked positions
  int   has_un = 0;
  unsigned hist = 0u;             // spike bits for times [t-10 .. t]
  float vd0 = 0.f, vd1 = 0.f, vd2 = 0.f, vd3 = 0.f, vd4 = 0.f, vd5 = 0.f;

  auto step = [&](float v, int t) {
    // delay line: vd_k = v[t-k] after this shift (pure renaming when unrolled)
    vd5 = vd4; vd4 = vd3; vd3 = vd2; vd2 = vd1; vd1 = vd0; vd0 = v;

    const bool spike = v >= 0.0f;
    const bool isstart = spike && ((t - last_spike) > CGAP);
    // close previous cluster (strict < keeps first minimal = argmin ties)
    const bool better = isstart && (nclu > 0) && (cur_count < best_count);
    best_count = better ? cur_count : best_count;
    best_max   = better ? cur_maxlast : best_max;
    nclu += isstart ? 1 : 0;
    cur_max = isstart ? v : fmaxf(cur_max, v);
    cur_maxlast = spike ? cur_max : cur_maxlast;  // snapshot at spikes only
    cur_count = isstart ? 0 : cur_count;
    cur_count += spike ? 1 : 0;
    last_spike = spike ? t : last_spike;

    // unmask decision for p = t - C: window [p-5, p+5] == hist's 11 bits
    hist = ((hist << 1) | (spike ? 1u : 0u)) & 0x7FFu;
    const bool un = (hist == 0u) && (t >= CGAP);
    umax = un ? fmaxf(umax, vd5) : umax;
    has_un |= un ? 1 : 0;
  };

  float xa[CH], xb[CH];
  // prefetch chunk 0
#pragma unroll
  for (int r = 0; r < CH; ++r) xa[r] = g[(size_t)r * NDIM];

  for (int c = 0; c < NCH; c += 2) {
    const int t0 = c * CH;
    // prefetch chunk c+1 (always exists: c even, c <= 30 -> c+1 <= 31)
#pragma unroll
    for (int r = 0; r < CH; ++r) xb[r] = g[(size_t)(t0 + CH + r) * NDIM];
    // process chunk c while chunk c+1 is in flight
#pragma unroll
    for (int r = 0; r < CH; ++r) step(xa[r], t0 + r);
    // prefetch chunk c+2 (skip past end)
    if (c + 2 < NCH) {
#pragma unroll
      for (int r = 0; r < CH; ++r) xa[r] = g[(size_t)(t0 + 2 * CH + r) * NDIM];
    }
    // process chunk c+1
#pragma unroll
    for (int r = 0; r < CH; ++r) step(xb[r], t0 + CH + r);
  }

  // epilogue: decide positions p = T-6+j for j=1..5
#pragma unroll
  for (int j = 1; j <= CGAP; ++j) {
    hist = (hist << 1) & 0x7FFu;
    vd5 = vd4; vd4 = vd3; vd3 = vd2; vd2 = vd1; vd1 = vd0; vd0 = -INFINITY;
    const bool un = (hist == 0u);
    umax = un ? fmaxf(umax, vd5) : umax;
    has_un |= un ? 1 : 0;
  }
  // close final cluster
  if (nclu > 0 && cur_count < best_count) best_max = cur_maxlast;

  const float ncf    = (float)nclu;
  const float margin = DELTA_C * ratio * ncf;
  // has_un==0 (full dilation coverage) is probabilistically impossible at
  // p(spike)=6.7%, T=512; reference would use a threefry-random spike there.
  const float under_term = has_un ? (-umax) : 0.0f;
  const float under = (label > nclu) ? (under_term + margin) : 0.0f;
  const float over  = (label < nclu) ? (best_max + margin) : 0.0f;

  out[1 + b * NDIM + n] = ncf;   // spike_output

  float sum = under + over;
#pragma unroll
  for (int off = 32; off > 0; off >>= 1) sum += __shfl_down(sum, off);
  if (lane == 0) atomicAdd(out, sum);    // loss
}

extern "C" void kernel_launch(void* const* d_in, const int* in_sizes, int n_in,
                              void* d_out, int out_size, void* d_ws,
                              size_t ws_size, hipStream_t stream) {
  const float* vmem   = (const float*)d_in[0];
  // d_in[1] (vlastmem) is unused by the loss math -> never read (saves 64 MiB)
  const int*   labels = (const int*)d_in[2];
  const float* ratio  = (const float*)d_in[3];
  float* out = (float*)d_out;

  hipMemsetAsync(d_out, 0, sizeof(float), stream);  // zero the loss accumulator
  dim3 grid(BDIM * (NDIM / 64));   // 512 single-wave blocks
  dim3 block(64);
  hipLaunchKernelGGL(stca_kernel, grid, block, 0, stream, vmem, labels, ratio,
                     out);
}